// Round 3
// baseline (2269.913 us; speedup 1.0000x reference)
//
#include <hip/hip_runtime.h>

// ---------------- types / helpers ----------------
typedef unsigned short u16;
typedef unsigned int   u32;
typedef __bf16 bf16x8 __attribute__((ext_vector_type(8)));
typedef float  f32x4  __attribute__((ext_vector_type(4)));

__device__ __forceinline__ u16 f2bf(float f) {
    u32 u = __builtin_bit_cast(u32, f);
    u = u + 0x7fffu + ((u >> 16) & 1u);
    return (u16)(u >> 16);
}
__device__ __forceinline__ float bflo(u32 u) { return __builtin_bit_cast(float, u << 16); }
__device__ __forceinline__ float bfhi(u32 u) { return __builtin_bit_cast(float, u & 0xffff0000u); }
__device__ __forceinline__ u32 pack2(float x, float y) { return (u32)f2bf(x) | ((u32)f2bf(y) << 16); }

// global -> LDS direct copy, 16B per lane. LDS dest is wave-uniform base (+lane*16 by HW).
__device__ __forceinline__ void gll16(const u16* g, u16* l) {
    __builtin_amdgcn_global_load_lds(
        (const __attribute__((address_space(1))) void*)g,
        (__attribute__((address_space(3))) void*)l, 16, 0, 0);
}

#define NN 100000
#define EE 400000
#define DP 320   // padded D (300 -> 320)
#define HP 640   // padded 2D (600 -> 640)

// ---------------- preprocessing ----------------
__global__ void count_deg(const int* __restrict__ ei, int* __restrict__ deg, int E) {
    int e = blockIdx.x * 256 + threadIdx.x;
    if (e < E) atomicAdd(&deg[ei[E + e]], 1);
}

__global__ void scan1(const int* __restrict__ deg, int* __restrict__ out, int* __restrict__ bsums, int n) {
    __shared__ int lds[1024];
    int t = threadIdx.x;
    int i = blockIdx.x * 1024 + t;
    int v = (i < n) ? deg[i] : 0;
    lds[t] = v;
    __syncthreads();
    for (int d = 1; d < 1024; d <<= 1) {
        int add = (t >= d) ? lds[t - d] : 0;
        __syncthreads();
        lds[t] += add;
        __syncthreads();
    }
    if (i < n) out[i] = lds[t] - v;   // exclusive
    if (t == 1023) bsums[blockIdx.x] = lds[t];
}

__global__ void scan2(int* __restrict__ bsums, int nb) {
    __shared__ int lds[128];
    int t = threadIdx.x;
    int v = (t < nb) ? bsums[t] : 0;
    lds[t] = v;
    __syncthreads();
    for (int d = 1; d < 128; d <<= 1) {
        int add = (t >= d) ? lds[t - d] : 0;
        __syncthreads();
        lds[t] += add;
        __syncthreads();
    }
    if (t < nb) bsums[t] = lds[t] - v;
}

__global__ void scan3(int* __restrict__ out, const int* __restrict__ bsums, int n, int etot) {
    int i = blockIdx.x * 1024 + threadIdx.x;
    if (i < n) out[i] += bsums[blockIdx.x];
    else if (i == n) out[i] = etot;
}

__global__ void fill_csr(const int* __restrict__ ei, const int* __restrict__ ea,
                         int* __restrict__ cursors, u32* __restrict__ vals, int E) {
    int e = blockIdx.x * 256 + threadIdx.x;
    if (e >= E) return;
    int dst = ei[E + e];
    int src = ei[e];
    u32 code = (u32)((ea[e*4] & 1) | ((ea[e*4+1] & 1) << 1) | ((ea[e*4+2] & 1) << 2) | ((ea[e*4+3] & 1) << 3));
    int pos = atomicAdd(&cursors[dst], 1);
    vals[pos] = ((u32)src << 4) | code;
}

// W1 -> transposed padded bf16, pre-swizzled image (XOR of 16B-unit index with n&7 within row).
// fused_mlp stages linearly into LDS and applies the same XOR on read -> 2-way banks.
__global__ void conv_w1(const float* __restrict__ w, u16* __restrict__ wt) {
    int id = blockIdx.x * 256 + threadIdx.x;
    if (id >= 5 * HP * DP) return;
    int l = id / (HP * DP);
    int rem = id - l * (HP * DP);
    int n = rem / DP;
    int kidx = rem - n * DP;
    int u = kidx >> 3, e = kidx & 7;
    int kk = ((u ^ (n & 7)) << 3) | e;
    u16 v = 0;
    if (n < 600 && kk < 300) v = f2bf(w[((size_t)l * 300 + kk) * 600 + n]);
    wt[id] = v;
}
// W2 -> [320 n][640 k] bf16, pre-swizzled: within each 4-unit (32-k) chunk group,
// physical unit u2 holds logical unit u2 ^ ((n>>1)&3).  Read applies the same XOR.
__global__ void conv_w2(const float* __restrict__ w, u16* __restrict__ wt) {
    int id = blockIdx.x * 256 + threadIdx.x;
    if (id >= 5 * DP * HP) return;
    int l = id / (DP * HP);
    int rem = id - l * (DP * HP);
    int n = rem / HP;
    int kp = rem - n * HP;
    int up = kp >> 3, e = kp & 7;
    int ul = (up & ~3) | ((up & 3) ^ ((n >> 1) & 3));
    int kk = (ul << 3) | e;
    u16 v = 0;
    if (n < 300 && kk < 600) v = f2bf(w[((size_t)l * 600 + kk) * 300 + n]);
    wt[id] = v;
}

// atom encoder -> y bf16
__global__ void atom_enc(const int* __restrict__ x, const float* __restrict__ at, u16* __restrict__ y) {
    const int i = blockIdx.x;
    const int d = threadIdx.x; // 0..319
    __shared__ int xi[7];
    if (d < 7) xi[d] = x[i * 7 + d];
    __syncthreads();
    u16 v = 0;
    if (d < 300) {
        float s = 0.f;
        #pragma unroll
        for (int f = 0; f < 7; ++f) s += at[(f * 119 + xi[f]) * 300 + d];
        v = f2bf(s);
    }
    y[(size_t)i * DP + d] = v;
}

// per-layer bond embedding table: 16 codes + self-loop (index 16)
__global__ void bond_enc(const float* __restrict__ bt, float* __restrict__ emb) {
    const int c = blockIdx.x;  // 0..16
    const int d = threadIdx.x; // 0..319
    float s = 0.f;
    if (d < 300) {
        if (c < 16) {
            #pragma unroll
            for (int f = 0; f < 4; ++f) s += bt[(f * 6 + ((c >> f) & 1)) * 300 + d];
        } else {
            s = bt[4 * 300 + d];  // bond[0][4]
            #pragma unroll
            for (int f = 1; f < 4; ++f) s += bt[f * 6 * 300 + d];
        }
    }
    emb[c * DP + d] = s;
}

// stats -> BN (scale, shift)
__global__ void bn_ss(const float* __restrict__ stats, const float* __restrict__ gamma,
                      const float* __restrict__ beta, float* __restrict__ scale,
                      float* __restrict__ shift, int n) {
    int d = threadIdx.x;
    float sc = 0.f, sh = 0.f;
    if (d < 300) {
        float inv_n = 1.0f / (float)n;
        float mu = stats[d] * inv_n;
        float var = stats[DP + d] * inv_n - mu * mu;
        float inv = 1.0f / sqrtf(var + 1e-5f);
        sc = gamma[d] * inv;
        sh = beta[d] - mu * sc;
    }
    scale[d] = sc; shift[d] = sh;
}

// y[i][d] = bf16(relu(scale*h_raw + shift))
__global__ void bn_apply(const float* __restrict__ hraw, const float* __restrict__ scale,
                         const float* __restrict__ shift, u16* __restrict__ y) {
    const int i = blockIdx.x;
    const int d = threadIdx.x;
    float v = fmaf(scale[d], hraw[(size_t)i * DP + d], shift[d]);
    y[(size_t)i * DP + d] = f2bf(fmaxf(v, 0.f));
}

// ---------------- aggregation: one wave per node ----------------
__global__ void aggregate(const u16* __restrict__ y,
                          const float* __restrict__ emb,
                          const int* __restrict__ offs, const u32* __restrict__ vals,
                          u16* __restrict__ agg, const int n) {
    const int wid = (int)((blockIdx.x * (size_t)blockDim.x + threadIdx.x) >> 6);
    const int lane = threadIdx.x & 63;
    if (wid >= n) return;
    const int j0 = lane, j1 = lane + 64, j2 = lane + 128;
    const bool has2 = (lane < 32);

    float a0x = 0.f, a0y = 0.f, a1x = 0.f, a1y = 0.f, a2x = 0.f, a2y = 0.f;

    auto accum = [&](int srcrow, const float* erow) {
        const u32* row = (const u32*)y + (size_t)srcrow * (DP / 2);
        u32 u0 = row[j0], u1 = row[j1];
        u32 u2 = has2 ? row[j2] : 0u;
        float2 e0 = *(const float2*)(erow + 2 * j0);
        float2 e1 = *(const float2*)(erow + 2 * j1);
        a0x += bflo(u0) + e0.x;  a0y += bfhi(u0) + e0.y;
        a1x += bflo(u1) + e1.x;  a1y += bfhi(u1) + e1.y;
        if (has2) {
            float2 e2 = *(const float2*)(erow + 2 * j2);
            a2x += bflo(u2) + e2.x;  a2y += bfhi(u2) + e2.y;
        }
    };

    accum(wid, emb + 16 * DP);            // self loop
    const int s = offs[wid], t = offs[wid + 1];
    for (int e = s; e < t; ++e) {
        u32 v = vals[e];
        accum((int)(v >> 4), emb + (v & 15u) * DP);
    }

    u32* out = (u32*)agg + (size_t)wid * (DP / 2);
    out[j0] = pack2(a0x, a0y);
    out[j1] = pack2(a1x, a1y);
    if (has2) out[j2] = pack2(a2x, a2y);
}

// ---------------- fused MLP ----------------
// 512 threads = 8 waves; block tile 128 rows.  Waves: mg = wave>>1 (32 rows, 2 mf of 16),
// ng = wave&1 (160-col half).  Every W-fragment ds_read feeds 2 MFMAs (mf reuse).
// Regs: afr[2][10]=80 + acc2[2][10]=80 + temps ~= 190 -> 1 block/CU (launch_bounds(512,2)).
// LDS 100,352 B: W1s dbuf 2x20,480 + W2s dbuf 2x20,480 + hidF (f32, stride 36) 18,432.
// All LDS accesses <=2-way banked.  One vmcnt-draining barrier per chunk (stage(c+1)
// issued at chunk top gets a full chunk of cover); mid hid-barrier is raw s_barrier +
// lgkmcnt(0) only, so the global_load_lds queue stays in flight across it.
__global__ __launch_bounds__(512, 2) void fused_mlp(
    const u16* __restrict__ A,      // agg [N][320] bf16
    const u16* __restrict__ W1t,    // [640][320] bf16, swizzled image
    const u16* __restrict__ W2t,    // [320][640] bf16, swizzled image
    const float* __restrict__ b1g,  // [600]
    const float* __restrict__ b2g,  // [300]
    float* __restrict__ H,          // h_raw [N][320] fp32
    float* __restrict__ st1, float* __restrict__ st2,
    const int M) {

    __shared__ __align__(16) u16 W1s[2 * 32 * 320];   // 40,960 B
    __shared__ __align__(16) u16 W2s[2 * 320 * 32];   // 40,960 B
    __shared__ __align__(16) float hidF[128 * 36];    // 18,432 B

    const int tid  = threadIdx.x;
    const int bm   = blockIdx.x * 128;
    const int wave = tid >> 6;
    const int lane = tid & 63;
    const int mg   = wave >> 1;       // 0..3
    const int ng   = wave & 1;        // 0..1
    const int l15  = lane & 15;
    const int q    = lane >> 4;

    // ---- prologue: stage W1/W2 slice 0 into buffer 0 ----
    for (int i = wave; i < 20; i += 8)
        gll16(W1t + (size_t)(i * 64 + lane) * 8, &W1s[i * 512]);
    {
        const u16* g2 = W2t;   // chunk 0
        for (int i = wave; i < 20; i += 8) {
            int u = i * 64 + lane;
            gll16(g2 + (size_t)(u >> 2) * HP + (u & 3) * 8, &W2s[i * 512]);
        }
    }

    // ---- A fragments straight from global (held whole kernel) ----
    bf16x8 afr[2][10];
    #pragma unroll
    for (int mf = 0; mf < 2; ++mf) {
        int arow = bm + mg * 32 + mf * 16 + l15;
        if (arow > M - 1) arow = M - 1;   // tail clamp; rows guarded in epilogue
        const u16* ap = A + (size_t)arow * DP + q * 8;
        #pragma unroll
        for (int kt = 0; kt < 10; ++kt)
            afr[mf][kt] = __builtin_bit_cast(bf16x8, *(const uint4*)(ap + kt * 32));
    }

    f32x4 acc2[2][10];
    const f32x4 zero4 = {0.f, 0.f, 0.f, 0.f};
    #pragma unroll
    for (int mf = 0; mf < 2; ++mf)
        #pragma unroll
        for (int nf = 0; nf < 10; ++nf) acc2[mf][nf] = zero4;

    __syncthreads();   // drains prologue staging + afr loads

    const int rr    = ng * 16 + l15;     // W1-slice row this lane reads
    const int rbase = rr * 320;
    const int r7    = l15 & 7;
    const int s2    = (l15 >> 1) & 3;    // W2 read swizzle

    for (int c = 0; c < 20; ++c) {
        const int p = c & 1;
        const u16* w1cur = W1s + p * 10240;
        const u16* w2cur = W2s + p * 10240;

        // ---- issue next-chunk staging (lands under the whole chunk) ----
        if (c < 19) {
            const u16* g1 = W1t + (size_t)(c + 1) * 10240;
            u16* l1 = W1s + (p ^ 1) * 10240;
            for (int i = wave; i < 20; i += 8)
                gll16(g1 + (size_t)(i * 64 + lane) * 8, l1 + i * 512);
            const u16* g2 = W2t + (size_t)(c + 1) * 32;
            u16* l2 = W2s + (p ^ 1) * 10240;
            for (int i = wave; i < 20; i += 8) {
                int u = i * 64 + lane;
                gll16(g2 + (size_t)(u >> 2) * HP + (u & 3) * 8, l2 + i * 512);
            }
        }

        // ---- GEMM1: 32 rows (2 mf) x 16 hidden cols, K=320 ----
        f32x4 acc1[2] = {zero4, zero4};
        #pragma unroll
        for (int kt = 0; kt < 10; ++kt) {
            uint4 t = *(const uint4*)&w1cur[rbase + ((((kt * 4 + q)) ^ r7) << 3)];
            bf16x8 b = __builtin_bit_cast(bf16x8, t);
            acc1[0] = __builtin_amdgcn_mfma_f32_16x16x32_bf16(afr[0][kt], b, acc1[0], 0, 0, 0);
            acc1[1] = __builtin_amdgcn_mfma_f32_16x16x32_bf16(afr[1][kt], b, acc1[1], 0, 0, 0);
        }
        // bias + relu -> hidF (f32, stride 36: 2-way banks)
        {
            int gcol = c * 32 + ng * 16 + l15;
            float bb = (gcol < 600) ? b1g[gcol] : 0.f;
            #pragma unroll
            for (int mf = 0; mf < 2; ++mf)
                #pragma unroll
                for (int r = 0; r < 4; ++r)
                    hidF[(mg * 32 + mf * 16 + q * 4 + r) * 36 + ng * 16 + l15] =
                        fmaxf(acc1[mf][r] + bb, 0.f);
        }
        // mid barrier: LDS-only drain; global_load_lds queue stays in flight
        asm volatile("s_waitcnt lgkmcnt(0)" ::: "memory");
        __builtin_amdgcn_s_barrier();
        __builtin_amdgcn_sched_barrier(0);

        // ---- a2 fragments from hidF (f32 -> bf16 pack) ----
        bf16x8 a2[2];
        #pragma unroll
        for (int mf = 0; mf < 2; ++mf) {
            const float* hp = &hidF[(mg * 32 + mf * 16 + l15) * 36 + q * 8];
            f32x4 lo = *(const f32x4*)hp;
            f32x4 hi = *(const f32x4*)(hp + 4);
            uint4 w;
            w.x = pack2(lo[0], lo[1]);
            w.y = pack2(lo[2], lo[3]);
            w.z = pack2(hi[0], hi[1]);
            w.w = pack2(hi[2], hi[3]);
            a2[mf] = __builtin_bit_cast(bf16x8, w);
        }
        // ---- GEMM2: acc2 += hid(32x32) @ W2slice(32x160) ----
        #pragma unroll
        for (int nf = 0; nf < 10; ++nf) {
            int row = ng * 160 + nf * 16 + l15;
            uint4 t = *(const uint4*)&w2cur[row * 32 + ((q ^ s2) << 3)];
            bf16x8 b = __builtin_bit_cast(bf16x8, t);
            acc2[0][nf] = __builtin_amdgcn_mfma_f32_16x16x32_bf16(a2[0], b, acc2[0][nf], 0, 0, 0);
            acc2[1][nf] = __builtin_amdgcn_mfma_f32_16x16x32_bf16(a2[1], b, acc2[1][nf], 0, 0, 0);
        }
        __syncthreads();   // drains staging for c+1; protects dbuf parity + hidF WAR
    }

    // ---- epilogue: bias2, store fp32 raw h, BN stats ----
    #pragma unroll
    for (int nf = 0; nf < 10; ++nf) {
        const int col = ng * 160 + nf * 16 + l15;
        const float bb = (col < 300) ? b2g[col] : 0.f;
        float s1 = 0.f, s2v = 0.f;
        #pragma unroll
        for (int mf = 0; mf < 2; ++mf)
            #pragma unroll
            for (int r = 0; r < 4; ++r) {
                const int row = bm + mg * 32 + mf * 16 + q * 4 + r;
                if (row < M) {
                    float v = acc2[mf][nf][r] + bb;
                    H[(size_t)row * DP + col] = v;
                    s1 += v; s2v += v * v;
                }
            }
        s1 += __shfl_xor(s1, 16); s1 += __shfl_xor(s1, 32);
        s2v += __shfl_xor(s2v, 16); s2v += __shfl_xor(s2v, 32);
        if (q == 0) { atomicAdd(&st1[col], s1); atomicAdd(&st2[col], s2v); }
    }
}

// final: d_out[i][d] = scale[d]*raw[i][d] + shift[d]
__global__ void finalize(const float* __restrict__ hraw, const float* __restrict__ scale,
                         const float* __restrict__ shift, float* __restrict__ out) {
    const int i = blockIdx.x;
    const int d = threadIdx.x;
    if (d < 300) {
        float x = hraw[(size_t)i * DP + d];
        out[(size_t)i * 300 + d] = fmaf(scale[d], x, shift[d]);
    }
}

// ---------------- launcher ----------------
extern "C" void kernel_launch(void* const* d_in, const int* in_sizes, int n_in,
                              void* d_out, int out_size, void* d_ws, size_t ws_size,
                              hipStream_t stream) {
    const int N = NN, E = EE, L = 5;
    const int*   x     = (const int*)d_in[0];
    const int*   ei    = (const int*)d_in[1];
    const int*   ea    = (const int*)d_in[2];
    const float* at    = (const float*)d_in[3];
    const float* bt    = (const float*)d_in[4];
    const float* w1    = (const float*)d_in[5];
    const float* b1    = (const float*)d_in[6];
    const float* w2    = (const float*)d_in[7];
    const float* b2    = (const float*)d_in[8];
    const float* gamma = (const float*)d_in[9];
    const float* beta  = (const float*)d_in[10];
    float* out = (float*)d_out;

    char* ws = (char*)d_ws;
    size_t off = 0;
    auto alloc = [&](size_t bytes) { char* p = ws + off; off = (off + bytes + 255) & ~(size_t)255; return p; };
    u16* buf_y    = (u16*)alloc((size_t)N * DP * 2);     // post-BN/relu state, bf16
    u16* buf_agg  = (u16*)alloc((size_t)N * DP * 2);
    float* buf_h  = (float*)alloc((size_t)N * DP * 4);   // raw (pre-BN) state, fp32
    u16* w1t      = (u16*)alloc((size_t)5 * HP * DP * 2);
    u16* w2t      = (u16*)alloc((size_t)5 * DP * HP * 2);
    int* deg      = (int*)alloc((size_t)N * 4);
    int* offs     = (int*)alloc((size_t)(N + 1) * 4);
    int* cursors  = (int*)alloc((size_t)N * 4);
    u32* vals     = (u32*)alloc((size_t)E * 4);
    int* bsums    = (int*)alloc(128 * 4);
    float* emb    = (float*)alloc(17 * DP * 4);
    float* stats  = (float*)alloc(2 * DP * 4);
    float* scale  = (float*)alloc(DP * 4);
    float* shift  = (float*)alloc(DP * 4);

    // CSR build (once per call; reused by all 5 layers)
    (void)hipMemsetAsync(deg, 0, (size_t)N * 4, stream);
    count_deg<<<(E + 255) / 256, 256, 0, stream>>>(ei, deg, E);
    const int nb = (N + 1023) / 1024;
    scan1<<<nb, 1024, 0, stream>>>(deg, offs, bsums, N);
    scan2<<<1, 128, 0, stream>>>(bsums, nb);
    scan3<<<(N + 1 + 1023) / 1024, 1024, 0, stream>>>(offs, bsums, N, E);
    (void)hipMemcpyAsync(cursors, offs, (size_t)N * 4, hipMemcpyDeviceToDevice, stream);
    fill_csr<<<(E + 255) / 256, 256, 0, stream>>>(ei, ea, cursors, vals, E);

    // weights -> bf16 transposed padded, pre-swizzled images
    conv_w1<<<(5 * HP * DP + 255) / 256, 256, 0, stream>>>(w1, w1t);
    conv_w2<<<(5 * DP * HP + 255) / 256, 256, 0, stream>>>(w2, w2t);

    // layer-0 state
    atom_enc<<<N, DP, 0, stream>>>(x, at, buf_y);

    const int MB = (N + 127) / 128; // 782
    for (int l = 0; l < L; ++l) {
        bond_enc<<<17, DP, 0, stream>>>(bt + (size_t)l * 4 * 6 * 300, emb);
        aggregate<<<(N * 64 + 255) / 256, 256, 0, stream>>>(
            buf_y, emb, offs, vals, buf_agg, N);
        (void)hipMemsetAsync(stats, 0, 2 * DP * 4, stream);
        fused_mlp<<<MB, 512, 0, stream>>>(
            buf_agg,
            w1t + (size_t)l * HP * DP, w2t + (size_t)l * DP * HP,
            b1 + (size_t)l * 600, b2 + (size_t)l * 300,
            buf_h, stats, stats + DP, N);
        bn_ss<<<1, DP, 0, stream>>>(stats, gamma + (size_t)l * 300, beta + (size_t)l * 300, scale, shift, N);
        if (l < L - 1)
            bn_apply<<<N, DP, 0, stream>>>(buf_h, scale, shift, buf_y);
    }
    finalize<<<N, DP, 0, stream>>>(buf_h, scale, shift, out);
}

// Round 4
// 1993.080 us; speedup vs baseline: 1.1389x; 1.1389x over previous
//
#include <hip/hip_runtime.h>

// ---------------- types / helpers ----------------
typedef unsigned short u16;
typedef unsigned int   u32;
typedef __bf16 bf16x8 __attribute__((ext_vector_type(8)));
typedef float  f32x4  __attribute__((ext_vector_type(4)));

__device__ __forceinline__ u16 f2bf(float f) {
    u32 u = __builtin_bit_cast(u32, f);
    u = u + 0x7fffu + ((u >> 16) & 1u);
    return (u16)(u >> 16);
}
__device__ __forceinline__ float bflo(u32 u) { return __builtin_bit_cast(float, u << 16); }
__device__ __forceinline__ float bfhi(u32 u) { return __builtin_bit_cast(float, u & 0xffff0000u); }
__device__ __forceinline__ u32 pack2(float x, float y) { return (u32)f2bf(x) | ((u32)f2bf(y) << 16); }

// global -> LDS direct copy, 16B per lane. LDS dest is wave-uniform base (+lane*16 by HW).
__device__ __forceinline__ void gll16(const u16* g, u16* l) {
    __builtin_amdgcn_global_load_lds(
        (const __attribute__((address_space(1))) void*)g,
        (__attribute__((address_space(3))) void*)l, 16, 0, 0);
}

#define NN 100000
#define EE 400000
#define DP 320   // padded D (300 -> 320)
#define HP 640   // padded 2D (600 -> 640)

// ---------------- preprocessing ----------------
__global__ void count_deg(const int* __restrict__ ei, int* __restrict__ deg, int E) {
    int e = blockIdx.x * 256 + threadIdx.x;
    if (e < E) atomicAdd(&deg[ei[E + e]], 1);
}

__global__ void scan1(const int* __restrict__ deg, int* __restrict__ out, int* __restrict__ bsums, int n) {
    __shared__ int lds[1024];
    int t = threadIdx.x;
    int i = blockIdx.x * 1024 + t;
    int v = (i < n) ? deg[i] : 0;
    lds[t] = v;
    __syncthreads();
    for (int d = 1; d < 1024; d <<= 1) {
        int add = (t >= d) ? lds[t - d] : 0;
        __syncthreads();
        lds[t] += add;
        __syncthreads();
    }
    if (i < n) out[i] = lds[t] - v;   // exclusive
    if (t == 1023) bsums[blockIdx.x] = lds[t];
}

__global__ void scan2(int* __restrict__ bsums, int nb) {
    __shared__ int lds[128];
    int t = threadIdx.x;
    int v = (t < nb) ? bsums[t] : 0;
    lds[t] = v;
    __syncthreads();
    for (int d = 1; d < 128; d <<= 1) {
        int add = (t >= d) ? lds[t - d] : 0;
        __syncthreads();
        lds[t] += add;
        __syncthreads();
    }
    if (t < nb) bsums[t] = lds[t] - v;
}

__global__ void scan3(int* __restrict__ out, const int* __restrict__ bsums, int n, int etot) {
    int i = blockIdx.x * 1024 + threadIdx.x;
    if (i < n) out[i] += bsums[blockIdx.x];
    else if (i == n) out[i] = etot;
}

__global__ void fill_csr(const int* __restrict__ ei, const int* __restrict__ ea,
                         int* __restrict__ cursors, u32* __restrict__ vals, int E) {
    int e = blockIdx.x * 256 + threadIdx.x;
    if (e >= E) return;
    int dst = ei[E + e];
    int src = ei[e];
    u32 code = (u32)((ea[e*4] & 1) | ((ea[e*4+1] & 1) << 1) | ((ea[e*4+2] & 1) << 2) | ((ea[e*4+3] & 1) << 3));
    int pos = atomicAdd(&cursors[dst], 1);
    vals[pos] = ((u32)src << 4) | code;
}

// W1 -> transposed padded bf16, pre-swizzled image (XOR of 16B-unit index with n&7 within row).
// fused_mlp stages linearly into LDS and applies the same XOR on read -> 2-way banks.
__global__ void conv_w1(const float* __restrict__ w, u16* __restrict__ wt) {
    int id = blockIdx.x * 256 + threadIdx.x;
    if (id >= 5 * HP * DP) return;
    int l = id / (HP * DP);
    int rem = id - l * (HP * DP);
    int n = rem / DP;
    int kidx = rem - n * DP;
    int u = kidx >> 3, e = kidx & 7;
    int kk = ((u ^ (n & 7)) << 3) | e;
    u16 v = 0;
    if (n < 600 && kk < 300) v = f2bf(w[((size_t)l * 300 + kk) * 600 + n]);
    wt[id] = v;
}
// W2 -> [320 n][640 k] bf16, pre-swizzled for 64-col phases:
// within each 64-col phase (8 16B units), physical unit j holds logical j ^ (n&7).
__global__ void conv_w2(const float* __restrict__ w, u16* __restrict__ wt) {
    int id = blockIdx.x * 256 + threadIdx.x;
    if (id >= 5 * DP * HP) return;
    int l = id / (DP * HP);
    int rem = id - l * (DP * HP);
    int n = rem / HP;
    int kp = rem - n * HP;          // physical col 0..639
    int c = kp >> 6;                // 64-col phase
    int j = (kp >> 3) & 7;          // physical unit within phase
    int e = kp & 7;
    int kk = c * 64 + ((j ^ (n & 7)) << 3) + e;   // logical k
    u16 v = 0;
    if (n < 300 && kk < 600) v = f2bf(w[((size_t)l * 600 + kk) * 300 + n]);
    wt[id] = v;
}

// atom encoder -> y bf16
__global__ void atom_enc(const int* __restrict__ x, const float* __restrict__ at, u16* __restrict__ y) {
    const int i = blockIdx.x;
    const int d = threadIdx.x; // 0..319
    __shared__ int xi[7];
    if (d < 7) xi[d] = x[i * 7 + d];
    __syncthreads();
    u16 v = 0;
    if (d < 300) {
        float s = 0.f;
        #pragma unroll
        for (int f = 0; f < 7; ++f) s += at[(f * 119 + xi[f]) * 300 + d];
        v = f2bf(s);
    }
    y[(size_t)i * DP + d] = v;
}

// per-layer bond embedding table: 16 codes + self-loop (index 16)
__global__ void bond_enc(const float* __restrict__ bt, float* __restrict__ emb) {
    const int c = blockIdx.x;  // 0..16
    const int d = threadIdx.x; // 0..319
    float s = 0.f;
    if (d < 300) {
        if (c < 16) {
            #pragma unroll
            for (int f = 0; f < 4; ++f) s += bt[(f * 6 + ((c >> f) & 1)) * 300 + d];
        } else {
            s = bt[4 * 300 + d];  // bond[0][4]
            #pragma unroll
            for (int f = 1; f < 4; ++f) s += bt[f * 6 * 300 + d];
        }
    }
    emb[c * DP + d] = s;
}

// stats -> BN (scale, shift)
__global__ void bn_ss(const float* __restrict__ stats, const float* __restrict__ gamma,
                      const float* __restrict__ beta, float* __restrict__ scale,
                      float* __restrict__ shift, int n) {
    int d = threadIdx.x;
    float sc = 0.f, sh = 0.f;
    if (d < 300) {
        float inv_n = 1.0f / (float)n;
        float mu = stats[d] * inv_n;
        float var = stats[DP + d] * inv_n - mu * mu;
        float inv = 1.0f / sqrtf(var + 1e-5f);
        sc = gamma[d] * inv;
        sh = beta[d] - mu * sc;
    }
    scale[d] = sc; shift[d] = sh;
}

// y[i][d] = bf16(relu(scale*h_raw + shift))
__global__ void bn_apply(const float* __restrict__ hraw, const float* __restrict__ scale,
                         const float* __restrict__ shift, u16* __restrict__ y) {
    const int i = blockIdx.x;
    const int d = threadIdx.x;
    float v = fmaf(scale[d], hraw[(size_t)i * DP + d], shift[d]);
    y[(size_t)i * DP + d] = f2bf(fmaxf(v, 0.f));
}

// ---------------- aggregation: one wave per node ----------------
__global__ void aggregate(const u16* __restrict__ y,
                          const float* __restrict__ emb,
                          const int* __restrict__ offs, const u32* __restrict__ vals,
                          u16* __restrict__ agg, const int n) {
    const int wid = (int)((blockIdx.x * (size_t)blockDim.x + threadIdx.x) >> 6);
    const int lane = threadIdx.x & 63;
    if (wid >= n) return;
    const int j0 = lane, j1 = lane + 64, j2 = lane + 128;
    const bool has2 = (lane < 32);

    float a0x = 0.f, a0y = 0.f, a1x = 0.f, a1y = 0.f, a2x = 0.f, a2y = 0.f;

    auto accum = [&](int srcrow, const float* erow) {
        const u32* row = (const u32*)y + (size_t)srcrow * (DP / 2);
        u32 u0 = row[j0], u1 = row[j1];
        u32 u2 = has2 ? row[j2] : 0u;
        float2 e0 = *(const float2*)(erow + 2 * j0);
        float2 e1 = *(const float2*)(erow + 2 * j1);
        a0x += bflo(u0) + e0.x;  a0y += bfhi(u0) + e0.y;
        a1x += bflo(u1) + e1.x;  a1y += bfhi(u1) + e1.y;
        if (has2) {
            float2 e2 = *(const float2*)(erow + 2 * j2);
            a2x += bflo(u2) + e2.x;  a2y += bfhi(u2) + e2.y;
        }
    };

    accum(wid, emb + 16 * DP);            // self loop
    const int s = offs[wid], t = offs[wid + 1];
    for (int e = s; e < t; ++e) {
        u32 v = vals[e];
        accum((int)(v >> 4), emb + (v & 15u) * DP);
    }

    u32* out = (u32*)agg + (size_t)wid * (DP / 2);
    out[j0] = pack2(a0x, a0y);
    out[j1] = pack2(a1x, a1y);
    if (has2) out[j2] = pack2(a2x, a2y);
}

// ---------------- fused MLP ----------------
// 512 threads = 8 waves; block tile 128 rows x 320 cols.
// 64-col hidden phases: 10 iterations, 2 barriers each (20 total, was 40).
// Per phase: GEMM1 = 40 MFMA + 20 ds_read_b128; GEMM2 = 40 MFMA + 20 reads.
// Single-buffered W slices; stage W1(c+1) after mid-barrier (GEMM2 covers it),
// stage W2(c+1) after end-barrier (next GEMM1 covers it).
// LDS 116,736 B: W1s 40,960 + W2s 40,960 + hidF (f32, stride 68) 34,816. 1 block/CU.
// Regs ~220 (afr 80 + acc2 80 + acc1 16 + a2 16 + temps) under the 256 cap of (512,2).
__global__ __launch_bounds__(512, 2) void fused_mlp(
    const u16* __restrict__ A,      // agg [N][320] bf16
    const u16* __restrict__ W1t,    // [640][320] bf16, swizzled image
    const u16* __restrict__ W2t,    // [320][640] bf16, swizzled image
    const float* __restrict__ b1g,  // [600]
    const float* __restrict__ b2g,  // [300]
    float* __restrict__ H,          // h_raw [N][320] fp32
    float* __restrict__ st1, float* __restrict__ st2,
    const int M) {

    __shared__ __align__(16) u16 W1s[64 * 320];    // 40,960 B
    __shared__ __align__(16) u16 W2s[320 * 64];    // 40,960 B
    __shared__ __align__(16) float hidF[128 * 68]; // 34,816 B

    const int tid  = threadIdx.x;
    const int bm   = blockIdx.x * 128;
    const int wave = tid >> 6;
    const int lane = tid & 63;
    const int mg   = wave >> 1;       // 0..3
    const int ng   = wave & 1;        // 0..1
    const int l15  = lane & 15;
    const int q    = lane >> 4;
    const int r7   = l15 & 7;

    // ---- prologue: stage W1/W2 phase 0 ----
    #pragma unroll
    for (int it = 0; it < 5; ++it) {
        int i = wave + it * 8;
        gll16(W1t + (size_t)(i * 64 + lane) * 8, &W1s[i * 512]);
    }
    #pragma unroll
    for (int it = 0; it < 5; ++it) {
        int i = wave + it * 8;
        int u = i * 64 + lane;                 // row = u>>3, unit j = u&7
        gll16(W2t + (size_t)(u >> 3) * HP + (u & 7) * 8, &W2s[i * 512]);
    }

    // ---- A fragments straight from global (held whole kernel) ----
    bf16x8 afr[2][10];
    #pragma unroll
    for (int mf = 0; mf < 2; ++mf) {
        int arow = bm + mg * 32 + mf * 16 + l15;
        if (arow > M - 1) arow = M - 1;   // tail clamp; rows guarded in epilogue
        const u16* ap = A + (size_t)arow * DP + q * 8;
        #pragma unroll
        for (int kt = 0; kt < 10; ++kt)
            afr[mf][kt] = __builtin_bit_cast(bf16x8, *(const uint4*)(ap + kt * 32));
    }

    f32x4 acc2[2][10];
    const f32x4 zero4 = {0.f, 0.f, 0.f, 0.f};
    #pragma unroll
    for (int mf = 0; mf < 2; ++mf)
        #pragma unroll
        for (int nf = 0; nf < 10; ++nf) acc2[mf][nf] = zero4;

    __syncthreads();   // drains prologue staging + afr loads

    for (int c = 0; c < 10; ++c) {
        // ---- GEMM1: 32 rows (2 mf) x 64 hidden cols (2 sc), K=320 ----
        f32x4 acc1[2][2] = {{zero4, zero4}, {zero4, zero4}};   // [sc][mf]
        __builtin_amdgcn_s_setprio(1);
        #pragma unroll
        for (int sc = 0; sc < 2; ++sc) {
            const int rb = (sc * 32 + ng * 16 + l15) * 320;
            #pragma unroll
            for (int kt = 0; kt < 10; ++kt) {
                uint4 t = *(const uint4*)&W1s[rb + (((kt * 4 + q) ^ r7) << 3)];
                bf16x8 b = __builtin_bit_cast(bf16x8, t);
                acc1[sc][0] = __builtin_amdgcn_mfma_f32_16x16x32_bf16(afr[0][kt], b, acc1[sc][0], 0, 0, 0);
                acc1[sc][1] = __builtin_amdgcn_mfma_f32_16x16x32_bf16(afr[1][kt], b, acc1[sc][1], 0, 0, 0);
            }
        }
        __builtin_amdgcn_s_setprio(0);
        // bias + relu -> hidF (f32, stride 68: 2-way banks)
        #pragma unroll
        for (int sc = 0; sc < 2; ++sc) {
            int gcol = c * 64 + sc * 32 + ng * 16 + l15;
            float bb = (gcol < 600) ? b1g[gcol] : 0.f;
            #pragma unroll
            for (int mf = 0; mf < 2; ++mf)
                #pragma unroll
                for (int r = 0; r < 4; ++r)
                    hidF[(mg * 32 + mf * 16 + q * 4 + r) * 68 + sc * 32 + ng * 16 + l15] =
                        fmaxf(acc1[sc][mf][r] + bb, 0.f);
        }
        __syncthreads();   // W1s reads + hid writes done; drains W2(c) staging (covered by prior GEMM1)

        // ---- stage W1(c+1): lands under GEMM2 ----
        if (c < 9) {
            const u16* g1 = W1t + (size_t)(c + 1) * 20480;
            #pragma unroll
            for (int it = 0; it < 5; ++it) {
                int i = wave + it * 8;
                gll16(g1 + (size_t)(i * 64 + lane) * 8, &W1s[i * 512]);
            }
        }

        // ---- a2 fragments from hidF (f32 -> bf16 pack), [mf][kq] ----
        bf16x8 a2[2][2];
        #pragma unroll
        for (int mf = 0; mf < 2; ++mf)
            #pragma unroll
            for (int kq = 0; kq < 2; ++kq) {
                const float* hp = &hidF[(mg * 32 + mf * 16 + l15) * 68 + kq * 32 + q * 8];
                f32x4 lo = *(const f32x4*)hp;
                f32x4 hi = *(const f32x4*)(hp + 4);
                uint4 w;
                w.x = pack2(lo[0], lo[1]);
                w.y = pack2(lo[2], lo[3]);
                w.z = pack2(hi[0], hi[1]);
                w.w = pack2(hi[2], hi[3]);
                a2[mf][kq] = __builtin_bit_cast(bf16x8, w);
            }
        // ---- GEMM2: acc2 += hid(32x64) @ W2slice(64x160) ----
        __builtin_amdgcn_s_setprio(1);
        #pragma unroll
        for (int nf = 0; nf < 10; ++nf) {
            const int row = ng * 160 + nf * 16 + l15;
            #pragma unroll
            for (int kq = 0; kq < 2; ++kq) {
                uint4 t = *(const uint4*)&W2s[row * 64 + (((kq * 4 + q) ^ r7) << 3)];
                bf16x8 b = __builtin_bit_cast(bf16x8, t);
                acc2[0][nf] = __builtin_amdgcn_mfma_f32_16x16x32_bf16(a2[0][kq], b, acc2[0][nf], 0, 0, 0);
                acc2[1][nf] = __builtin_amdgcn_mfma_f32_16x16x32_bf16(a2[1][kq], b, acc2[1][nf], 0, 0, 0);
            }
        }
        __builtin_amdgcn_s_setprio(0);
        __syncthreads();   // W2s + hidF reads done; drains W1(c+1) staging (covered by GEMM2)

        // ---- stage W2(c+1): lands under next GEMM1 ----
        if (c < 9) {
            const u16* g2 = W2t + (size_t)(c + 1) * 64;
            #pragma unroll
            for (int it = 0; it < 5; ++it) {
                int i = wave + it * 8;
                int u = i * 64 + lane;
                gll16(g2 + (size_t)(u >> 3) * HP + (u & 7) * 8, &W2s[i * 512]);
            }
        }
    }

    // ---- epilogue: bias2, store fp32 raw h, BN stats ----
    #pragma unroll
    for (int nf = 0; nf < 10; ++nf) {
        const int col = ng * 160 + nf * 16 + l15;
        const float bb = (col < 300) ? b2g[col] : 0.f;
        float s1 = 0.f, s2v = 0.f;
        #pragma unroll
        for (int mf = 0; mf < 2; ++mf)
            #pragma unroll
            for (int r = 0; r < 4; ++r) {
                const int row = bm + mg * 32 + mf * 16 + q * 4 + r;
                if (row < M) {
                    float v = acc2[mf][nf][r] + bb;
                    H[(size_t)row * DP + col] = v;
                    s1 += v; s2v += v * v;
                }
            }
        s1 += __shfl_xor(s1, 16); s1 += __shfl_xor(s1, 32);
        s2v += __shfl_xor(s2v, 16); s2v += __shfl_xor(s2v, 32);
        if (q == 0) { atomicAdd(&st1[col], s1); atomicAdd(&st2[col], s2v); }
    }
}

// final: d_out[i][d] = scale[d]*raw[i][d] + shift[d]
__global__ void finalize(const float* __restrict__ hraw, const float* __restrict__ scale,
                         const float* __restrict__ shift, float* __restrict__ out) {
    const int i = blockIdx.x;
    const int d = threadIdx.x;
    if (d < 300) {
        float x = hraw[(size_t)i * DP + d];
        out[(size_t)i * 300 + d] = fmaf(scale[d], x, shift[d]);
    }
}

// ---------------- launcher ----------------
extern "C" void kernel_launch(void* const* d_in, const int* in_sizes, int n_in,
                              void* d_out, int out_size, void* d_ws, size_t ws_size,
                              hipStream_t stream) {
    const int N = NN, E = EE, L = 5;
    const int*   x     = (const int*)d_in[0];
    const int*   ei    = (const int*)d_in[1];
    const int*   ea    = (const int*)d_in[2];
    const float* at    = (const float*)d_in[3];
    const float* bt    = (const float*)d_in[4];
    const float* w1    = (const float*)d_in[5];
    const float* b1    = (const float*)d_in[6];
    const float* w2    = (const float*)d_in[7];
    const float* b2    = (const float*)d_in[8];
    const float* gamma = (const float*)d_in[9];
    const float* beta  = (const float*)d_in[10];
    float* out = (float*)d_out;

    char* ws = (char*)d_ws;
    size_t off = 0;
    auto alloc = [&](size_t bytes) { char* p = ws + off; off = (off + bytes + 255) & ~(size_t)255; return p; };
    u16* buf_y    = (u16*)alloc((size_t)N * DP * 2);     // post-BN/relu state, bf16
    u16* buf_agg  = (u16*)alloc((size_t)N * DP * 2);
    float* buf_h  = (float*)alloc((size_t)N * DP * 4);   // raw (pre-BN) state, fp32
    u16* w1t      = (u16*)alloc((size_t)5 * HP * DP * 2);
    u16* w2t      = (u16*)alloc((size_t)5 * DP * HP * 2);
    int* deg      = (int*)alloc((size_t)N * 4);
    int* offs     = (int*)alloc((size_t)(N + 1) * 4);
    int* cursors  = (int*)alloc((size_t)N * 4);
    u32* vals     = (u32*)alloc((size_t)E * 4);
    int* bsums    = (int*)alloc(128 * 4);
    float* emb    = (float*)alloc(17 * DP * 4);
    float* stats  = (float*)alloc(2 * DP * 4);
    float* scale  = (float*)alloc(DP * 4);
    float* shift  = (float*)alloc(DP * 4);

    // CSR build (once per call; reused by all 5 layers)
    (void)hipMemsetAsync(deg, 0, (size_t)N * 4, stream);
    count_deg<<<(E + 255) / 256, 256, 0, stream>>>(ei, deg, E);
    const int nb = (N + 1023) / 1024;
    scan1<<<nb, 1024, 0, stream>>>(deg, offs, bsums, N);
    scan2<<<1, 128, 0, stream>>>(bsums, nb);
    scan3<<<(N + 1 + 1023) / 1024, 1024, 0, stream>>>(offs, bsums, N, E);
    (void)hipMemcpyAsync(cursors, offs, (size_t)N * 4, hipMemcpyDeviceToDevice, stream);
    fill_csr<<<(E + 255) / 256, 256, 0, stream>>>(ei, ea, cursors, vals, E);

    // weights -> bf16 transposed padded, pre-swizzled images
    conv_w1<<<(5 * HP * DP + 255) / 256, 256, 0, stream>>>(w1, w1t);
    conv_w2<<<(5 * DP * HP + 255) / 256, 256, 0, stream>>>(w2, w2t);

    // layer-0 state
    atom_enc<<<N, DP, 0, stream>>>(x, at, buf_y);

    const int MB = (N + 127) / 128; // 782
    for (int l = 0; l < L; ++l) {
        bond_enc<<<17, DP, 0, stream>>>(bt + (size_t)l * 4 * 6 * 300, emb);
        aggregate<<<(N * 64 + 255) / 256, 256, 0, stream>>>(
            buf_y, emb, offs, vals, buf_agg, N);
        (void)hipMemsetAsync(stats, 0, 2 * DP * 4, stream);
        fused_mlp<<<MB, 512, 0, stream>>>(
            buf_agg,
            w1t + (size_t)l * HP * DP, w2t + (size_t)l * DP * HP,
            b1 + (size_t)l * 600, b2 + (size_t)l * 300,
            buf_h, stats, stats + DP, N);
        bn_ss<<<1, DP, 0, stream>>>(stats, gamma + (size_t)l * 300, beta + (size_t)l * 300, scale, shift, N);
        if (l < L - 1)
            bn_apply<<<N, DP, 0, stream>>>(buf_h, scale, shift, buf_y);
    }
    finalize<<<N, DP, 0, stream>>>(buf_h, scale, shift, out);
}